// Round 6
// baseline (967.951 us; speedup 1.0000x reference)
//
#include <hip/hip_runtime.h>

#define DEVFN __device__ __forceinline__

typedef _Float16 f16x8 __attribute__((ext_vector_type(8)));
typedef float f32x4 __attribute__((ext_vector_type(4)));

static constexpr int T   = 8192;   // tokens (B*S)
static constexpr int D   = 1024;
static constexpr int E   = 8;
static constexpr int DFF = 4096;
static constexpr int NG  = E + 1;            // 8 experts + shared
static constexpr int RTOT = 3*T;             // 2T routed rows + T shared rows
static constexpr int MAXRT = (2*T)/128 + E + T/128;   // 128 + 8 + 64 = 200 row tiles (BM=128)

DEVFN unsigned short f2h_bits(float v){
  _Float16 h = (_Float16)v;           // RNE
  return __builtin_bit_cast(unsigned short, h);
}

DEVFN void gload_lds16(const void* g, void* l){
  __builtin_amdgcn_global_load_lds((const __attribute__((address_space(1))) void*)g,
                                   (__attribute__((address_space(3))) void*)l, 16, 0, 0);
}

// ---------------- single fused cast fp32 -> fp16 over all 4 weight tensors ----------------
__global__ __launch_bounds__(256) void cast_all_kernel(
    const float* __restrict__ s0, const float* __restrict__ s1,
    const float* __restrict__ s2, const float* __restrict__ s3,
    unsigned short* __restrict__ d0, unsigned short* __restrict__ d1,
    unsigned short* __restrict__ d2, unsigned short* __restrict__ d3,
    int n0, int n1, int n2, int n3){           // counts in float4 units
  int total = n0 + n1 + n2 + n3;
  for (int j = blockIdx.x*256 + threadIdx.x; j < total; j += gridDim.x*256){
    const float* sp; unsigned short* dp; int loc = j;
    if (loc < n0){ sp = s0; dp = d0; }
    else if ((loc -= n0) < n1){ sp = s1; dp = d1; }
    else if ((loc -= n1) < n2){ sp = s2; dp = d2; }
    else { loc -= n2; sp = s3; dp = d3; }
    float4 v = ((const float4*)sp)[loc];
    ushort4 o;
    o.x = f2h_bits(v.x); o.y = f2h_bits(v.y); o.z = f2h_bits(v.z); o.w = f2h_bits(v.w);
    ((ushort4*)dp)[loc] = o;
  }
}

// ---------------- router: fp32 logits, softmax-top2, counts; also emits xb (f16 x) ----------------
__global__ __launch_bounds__(256) void router_kernel(const float* __restrict__ x,
    const float* __restrict__ rw, unsigned short* __restrict__ xb,
    int* __restrict__ tok_e, float* __restrict__ tok_w, int* __restrict__ counts){
  const int lane = threadIdx.x & 63;
  const int t = blockIdx.x*4 + (threadIdx.x >> 6);
  const float4* xp = (const float4*)(x + (size_t)t*D);
  ushort4* xo = (ushort4*)(xb + (size_t)t*D);
  float acc[E];
#pragma unroll
  for (int e=0;e<E;e++) acc[e]=0.f;
#pragma unroll
  for (int i=0;i<4;i++){
    float4 xv = xp[lane + (i<<6)];
    ushort4 o; o.x=f2h_bits(xv.x); o.y=f2h_bits(xv.y); o.z=f2h_bits(xv.z); o.w=f2h_bits(xv.w);
    xo[lane + (i<<6)] = o;
#pragma unroll
    for (int e=0;e<E;e++){
      float4 wv = ((const float4*)(rw + e*D))[lane + (i<<6)];
      acc[e] = fmaf(xv.x,wv.x, fmaf(xv.y,wv.y, fmaf(xv.z,wv.z, fmaf(xv.w,wv.w, acc[e]))));
    }
  }
#pragma unroll
  for (int e=0;e<E;e++){
#pragma unroll
    for (int off=32; off>0; off>>=1) acc[e] += __shfl_xor(acc[e], off);
  }
  if (lane==0){
    float l0=-1e30f, l1=-1e30f; int e0=0, e1=0;
#pragma unroll
    for (int e=0;e<E;e++){
      float v = acc[e];
      if (v > l0){ l1=l0; e1=e0; l0=v; e0=e; }
      else if (v > l1){ l1=v; e1=e; }
    }
    float r   = expf(l1 - l0);          // p1/p0
    float inv = 1.f/(1.f + r);
    tok_e[2*t]   = e0; tok_e[2*t+1] = e1;
    tok_w[2*t]   = inv; tok_w[2*t+1] = r*inv;
    atomicAdd(&counts[e0], 1);
    atomicAdd(&counts[e1], 1);
  }
}

// ---------------- scan: offsets + row-tile map (9 groups, 128-row tiles) ----------------
__global__ void scan_kernel(const int* __restrict__ counts, int* __restrict__ offs,
                            int* __restrict__ tile_g, int* __restrict__ tile_r0,
                            int* __restrict__ nrt){
  if (blockIdx.x==0 && threadIdx.x==0){
    int off=0, nt=0;
    for (int e=0;e<E;e++){
      offs[e]=off;
      int c = counts[e];
      int tiles = (c+127)>>7;
      for (int i=0;i<tiles;i++){ tile_g[nt]=e; tile_r0[nt]=off + (i<<7); nt++; }
      off += c;
    }
    offs[E] = off;                       // == 2T
    for (int i=0;i<T/128;i++){ tile_g[nt]=E; tile_r0[nt]=2*T + (i<<7); nt++; }
    offs[E+1] = 3*T;
    *nrt = nt;
  }
}

// ---------------- scatter: grouped row -> token; inverse map token -> grouped rows ----------------
__global__ __launch_bounds__(256) void scatter_kernel(const int* __restrict__ tok_e,
    const float* __restrict__ tok_w, const int* __restrict__ offs,
    int* __restrict__ fill, int* __restrict__ row_tok, float* __restrict__ row_w,
    int* __restrict__ inv2){
  int idx = blockIdx.x*256 + threadIdx.x;   // [0, 3T)
  if (idx < 2*T){
    int e = tok_e[idx];
    int pos = offs[e] + atomicAdd(&fill[e], 1);
    row_tok[pos] = idx >> 1;
    row_w[pos]   = tok_w[idx];
    inv2[idx]    = pos;                     // inv2[2*token + slot]
  } else {
    row_tok[idx] = idx - 2*T;
    row_w[idx]   = 1.0f;
  }
}

// ---- grouped GEMM, 128x128 tile, BK=64, 2x2 waves (256 thr), ring-2 LDS (64 KB -> 2 blocks/CU).
//      Per K-tile: 2 phases, each {8 ds_read_b128 || stage 1 k-half (A+B, 4 gload_lds)
//                  -> vmcnt(4) -> bar -> setprio1 -> 16 MFMA -> setprio0 -> bar}.
//      Counted vmcnt: in-flight 4-8 loads; only final tile drains to 0.
// MODE 0: FC  (A = xb gathered via row_tok, out = relu(acc)^2 -> h f16)
// MODE 1: PROJ(A = h grouped-contiguous,    out = raw acc -> y f16; weights in combine)
template<int MODE>
__global__ __launch_bounds__(256, 2) void gemm8p_kernel(
    const unsigned short* __restrict__ A, const unsigned short* __restrict__ Ball,
    unsigned short* __restrict__ O,
    const int K, const int N, const int CT,
    const int* __restrict__ tile_g, const int* __restrict__ tile_r0,
    const int* __restrict__ offs, const int* __restrict__ nrt,
    const int* __restrict__ row_tok)
{
  // T1: bijective XCD swizzle on linearized wg id (m204 form)
  const int nwg  = gridDim.x * gridDim.y;
  const int orig = blockIdx.y * gridDim.x + blockIdx.x;
  const int q8 = nwg >> 3, r8 = nwg & 7;
  const int xcd = orig & 7, pos = orig >> 3;
  const int wg = (xcd < r8 ? xcd*(q8+1) : r8*(q8+1) + (xcd-r8)*q8) + pos;
  const int rt = wg / CT, ct = wg - rt*CT;
  if (rt >= *nrt) return;

  const int g    = tile_g[rt];
  const int row0 = tile_r0[rt];
  const int row_end = offs[g+1];
  const unsigned short* Bp = Ball + (size_t)g * (size_t)N * (size_t)K;

  // HT(buf,ks): 4096 shorts = [128 rows][4 x 16B chunks]; A,B each 2buf x 2khalf = 32 KB
  __shared__ __align__(16) unsigned short As[2*2*4096];
  __shared__ __align__(16) unsigned short Bs[2*2*4096];

  const int tid  = threadIdx.x;
  const int lane = tid & 63;
  const int wave = tid >> 6;

  // --- staging map: slot s = c*256+tid (512 slots); row rr = s>>2; local chunk = s&3;
  //     inverse-swizzled global chunk qg = (s&3) ^ ((rr>>1)&3)   (0-conflict family, r1-r4)
  const unsigned short* aS[2];
  const unsigned short* bS[2];
  int ldst[2];
#pragma unroll
  for (int c=0;c<2;c++){
    int s  = (c<<8) + tid;
    int rr = s >> 2;
    int qg = (s & 3) ^ ((rr >> 1) & 3);
    int ar;
    if constexpr (MODE==0){
      int grow = row0 + rr;
      if (grow > row_end-1) grow = row_end-1;   // clamp padded rows (output discarded)
      ar = row_tok[grow];
    } else {
      ar = row0 + rr;
    }
    aS[c] = A  + (size_t)ar*K + qg*8;
    bS[c] = Bp + (size_t)((ct<<7) + rr)*K + qg*8;
    ldst[c] = ((c<<8) + (wave<<6))*8;        // wave-uniform LDS base (lane*16B implicit)
  }

#define STAGE_A(KT,KS) { _Pragma("unroll") for (int c=0;c<2;c++) \
    gload_lds16(aS[c] + (KT)*64 + (KS)*32, As + ((((KT)&1)*2+(KS))<<12) + ldst[c]); }
#define STAGE_B(KT,KS) { _Pragma("unroll") for (int c=0;c<2;c++) \
    gload_lds16(bS[c] + (KT)*64 + (KS)*32, Bs + ((((KT)&1)*2+(KS))<<12) + ldst[c]); }

  // --- fragment read offsets within a half-tile [128][32] shorts (swizzle matches staging)
  const int wm = wave >> 1, wn = wave & 1;   // 2x2 waves, per-wave output 64 x 64
  const int q16g = lane >> 4;
  int aoff[4], boff[4];
#pragma unroll
  for (int m=0;m<4;m++){
    int r = (wm<<6) + (m<<4) + (lane&15);
    aoff[m] = (r<<5) + ((q16g ^ ((r>>1)&3))<<3);
  }
#pragma unroll
  for (int n=0;n<4;n++){
    int r = (wn<<6) + (n<<4) + (lane&15);
    boff[n] = (r<<5) + ((q16g ^ ((r>>1)&3))<<3);
  }

#define BARS { __builtin_amdgcn_s_barrier(); __builtin_amdgcn_sched_barrier(0); }
#define VMW(NN) asm volatile("s_waitcnt vmcnt(" #NN ")" ::: "memory");
#define DSA(BUF,KS) { const unsigned short* hb = As + (((BUF)*2+(KS))<<12); \
    _Pragma("unroll") for (int m=0;m<4;m++) af[m] = *(const f16x8*)(hb + aoff[m]); }
#define DSB(BUF,KS) { const unsigned short* hb = Bs + (((BUF)*2+(KS))<<12); \
    _Pragma("unroll") for (int n=0;n<4;n++) bf[n] = *(const f16x8*)(hb + boff[n]); }
#define MFMA16 { __builtin_amdgcn_s_setprio(1); \
    _Pragma("unroll") for (int m=0;m<4;m++) \
    _Pragma("unroll") for (int n=0;n<4;n++) \
      acc[m][n] = __builtin_amdgcn_mfma_f32_16x16x32_f16(af[m], bf[n], acc[m][n], 0, 0, 0); \
    __builtin_amdgcn_s_setprio(0); }

  f32x4 acc[4][4] = {};
  const int nkt = K >> 6;                    // 64-wide K tiles (16 FC / 64 PROJ)

  // prologue: stage tile0's two k-halves; retire k-half0 (oldest 4 of 8)
  STAGE_A(0,0); STAGE_B(0,0); STAGE_A(0,1); STAGE_B(0,1);
  VMW(4); BARS;

  f16x8 af[4], bf[4];
  for (int t=0; t<nkt; ++t){
    const int buf = t & 1;
    const bool more = (t+1 < nkt);
    // ---- phase 1: k-half 0
    DSA(buf,0); DSB(buf,0);
    if (more) { STAGE_A(t+1,0); STAGE_B(t+1,0); VMW(4); }
    else      { VMW(0); }
    BARS; MFMA16; BARS;
    // ---- phase 2: k-half 1
    DSA(buf,1); DSB(buf,1);
    if (more) { STAGE_A(t+1,1); STAGE_B(t+1,1); VMW(4); }
    BARS; MFMA16;
    if (more) BARS;
  }

  // --- epilogue: C row = (lane>>4)*4 + q, col = lane&15 within each 16x16 fragment
  const int lcol = lane & 15;
  const int lrow = (lane >> 4) << 2;
#pragma unroll
  for (int m=0;m<4;m++){
#pragma unroll
    for (int q=0;q<4;q++){
      const int grow = row0 + (wm<<6) + (m<<4) + lrow + q;
      if (grow >= row_end) continue;           // padded tile rows
#pragma unroll
      for (int n=0;n<4;n++){
        const int col = (ct<<7) + (wn<<6) + (n<<4) + lcol;
        float v = acc[m][n][q];
        if constexpr (MODE==0) v = (v > 0.f) ? v*v : 0.f;   // relu(x)^2
        O[(size_t)grow*N + col] = f2h_bits(v);
      }
    }
  }
#undef STAGE_A
#undef STAGE_B
#undef BARS
#undef VMW
#undef DSA
#undef DSB
#undef MFMA16
}

// ---------------- combine: out[t] = w0*y[p0] + w1*y[p1] + y[shared_t] ----------------
__global__ __launch_bounds__(256) void combine_kernel(const unsigned short* __restrict__ y,
    const int* __restrict__ inv2, const float* __restrict__ row_w, float* __restrict__ out){
  int gid = blockIdx.x*256 + threadIdx.x;    // T*128 threads, 8 cols each
  int t = gid >> 7, c = gid & 127;
  int p0 = inv2[2*t], p1 = inv2[2*t+1];
  float w0 = row_w[p0], w1 = row_w[p1];
  f16x8 v0 = *(const f16x8*)(y + (size_t)p0*D      + c*8);
  f16x8 v1 = *(const f16x8*)(y + (size_t)p1*D      + c*8);
  f16x8 v2 = *(const f16x8*)(y + (size_t)(2*T+t)*D + c*8);
  float4 o0, o1;
  float r[8];
#pragma unroll
  for (int j=0;j<8;j++)
    r[j] = fmaf(w0, (float)v0[j], fmaf(w1, (float)v1[j], (float)v2[j]));
  o0.x=r[0]; o0.y=r[1]; o0.z=r[2]; o0.w=r[3];
  o1.x=r[4]; o1.y=r[5]; o1.z=r[6]; o1.w=r[7];
  float4* op = (float4*)(out + (size_t)t*D + c*8);
  op[0] = o0; op[1] = o1;
}

// ---------------- host launcher ----------------
extern "C" void kernel_launch(void* const* d_in, const int* in_sizes, int n_in,
                              void* d_out, int out_size, void* d_ws, size_t ws_size,
                              hipStream_t stream){
  const float* x     = (const float*)d_in[0];
  const float* rw    = (const float*)d_in[1];
  const float* wfc   = (const float*)d_in[2];
  const float* wproj = (const float*)d_in[3];
  const float* sfc   = (const float*)d_in[4];
  const float* sproj = (const float*)d_in[5];
  float* out = (float*)d_out;

  char* ws = (char*)d_ws;
  size_t off = 0;
  auto alloc = [&](size_t bytes)->void*{
    void* p = ws + off; off += (bytes + 255) & ~(size_t)255; return p;
  };
  unsigned short* xb    = (unsigned short*)alloc((size_t)T*D*2);
  unsigned short* wall  = (unsigned short*)alloc((size_t)NG*DFF*D*2);  // experts 0..7 then shared
  unsigned short* wpall = (unsigned short*)alloc((size_t)NG*D*DFF*2);
  unsigned short* h     = (unsigned short*)alloc((size_t)RTOT*DFF*2);
  int*   tok_e   = (int*)  alloc((size_t)T*2*4);
  float* tok_w   = (float*)alloc((size_t)T*2*4);
  int*   row_tok = (int*)  alloc((size_t)RTOT*4);
  float* row_w   = (float*)alloc((size_t)RTOT*4);
  int*   inv2    = (int*)  alloc((size_t)2*T*4);
  int* counts  = (int*)alloc(E*4);
  int* fill    = (int*)alloc(E*4);
  int* offs    = (int*)alloc((E+2)*4);
  int* nrt     = (int*)alloc(4);
  int* tile_g  = (int*)alloc(MAXRT*4);
  int* tile_r0 = (int*)alloc(MAXRT*4);
  if (off > ws_size) return;   // visible failure if workspace too small

  // y [3T][D] f16 aliases wall: FC (last reader of wall) completes before PROJ writes y.
  unsigned short* y = wall;    // 50 MB needed, 75 MB available

  hipMemsetAsync(counts, 0, E*4, stream);
  hipMemsetAsync(fill,   0, E*4, stream);

  // single fused weight-cast dispatch (x cast fused into router)
  cast_all_kernel<<<2048, 256, 0, stream>>>(
      wfc, sfc, wproj, sproj,
      wall, wall + (size_t)E*DFF*D, wpall, wpall + (size_t)E*D*DFF,
      E*DFF*D/4, DFF*D/4, E*D*DFF/4, D*DFF/4);

  // routing
  router_kernel <<<T/4, 256, 0, stream>>>(x, rw, xb, tok_e, tok_w, counts);
  scan_kernel   <<<1,   64,  0, stream>>>(counts, offs, tile_g, tile_r0, nrt);
  scatter_kernel<<<RTOT/256, 256, 0, stream>>>(tok_e, tok_w, offs, fill, row_tok, row_w, inv2);

  // FC: h = relu(x @ w_fc^T)^2 for all grouped rows (incl. shared)
  gemm8p_kernel<0><<<dim3(DFF/128, MAXRT), 256, 0, stream>>>(
      xb, wall, h, D, DFF, DFF/128, tile_g, tile_r0, offs, nrt, row_tok);
  // PROJ: y = h @ w_proj^T (raw, unweighted)
  gemm8p_kernel<1><<<dim3(D/128, MAXRT), 256, 0, stream>>>(
      h, wpall, y, DFF, D, D/128, tile_g, tile_r0, offs, nrt, row_tok);
  // combine: weighted sum per token
  combine_kernel<<<(T*128)/256, 256, 0, stream>>>(y, inv2, row_w, out);
}

// Round 7
// 846.208 us; speedup vs baseline: 1.1439x; 1.1439x over previous
//
#include <hip/hip_runtime.h>

#define DEVFN __device__ __forceinline__

typedef _Float16 f16x8 __attribute__((ext_vector_type(8)));
typedef float f32x4 __attribute__((ext_vector_type(4)));

static constexpr int T   = 8192;   // tokens (B*S)
static constexpr int D   = 1024;
static constexpr int E   = 8;
static constexpr int DFF = 4096;
static constexpr int NG  = E + 1;            // 8 experts + shared
static constexpr int RTOT = 3*T;             // 2T routed rows + T shared rows
static constexpr int MAXRT = (2*T)/256 + E + T/256;   // 64 + 8 + 32 = 104 (256-row tiles)

DEVFN unsigned short f2h_bits(float v){
  _Float16 h = (_Float16)v;           // RNE
  return __builtin_bit_cast(unsigned short, h);
}

DEVFN void gload_lds16(const void* g, void* l){
  __builtin_amdgcn_global_load_lds((const __attribute__((address_space(1))) void*)g,
                                   (__attribute__((address_space(3))) void*)l, 16, 0, 0);
}

// ---------------- single fused cast fp32 -> fp16 over all 4 weight tensors ----------------
__global__ __launch_bounds__(256) void cast_all_kernel(
    const float* __restrict__ s0, const float* __restrict__ s1,
    const float* __restrict__ s2, const float* __restrict__ s3,
    unsigned short* __restrict__ d0, unsigned short* __restrict__ d1,
    unsigned short* __restrict__ d2, unsigned short* __restrict__ d3,
    int n0, int n1, int n2, int n3){           // counts in float4 units
  int total = n0 + n1 + n2 + n3;
  for (int j = blockIdx.x*256 + threadIdx.x; j < total; j += gridDim.x*256){
    const float* sp; unsigned short* dp; int loc = j;
    if (loc < n0){ sp = s0; dp = d0; }
    else if ((loc -= n0) < n1){ sp = s1; dp = d1; }
    else if ((loc -= n1) < n2){ sp = s2; dp = d2; }
    else { loc -= n2; sp = s3; dp = d3; }
    float4 v = ((const float4*)sp)[loc];
    ushort4 o;
    o.x = f2h_bits(v.x); o.y = f2h_bits(v.y); o.z = f2h_bits(v.z); o.w = f2h_bits(v.w);
    ((ushort4*)dp)[loc] = o;
  }
}

// ---------------- router: fp32 logits, softmax-top2, counts; also emits xb (f16 x) ----------------
__global__ __launch_bounds__(256) void router_kernel(const float* __restrict__ x,
    const float* __restrict__ rw, unsigned short* __restrict__ xb,
    int* __restrict__ tok_e, float* __restrict__ tok_w, int* __restrict__ counts){
  const int lane = threadIdx.x & 63;
  const int t = blockIdx.x*4 + (threadIdx.x >> 6);
  const float4* xp = (const float4*)(x + (size_t)t*D);
  ushort4* xo = (ushort4*)(xb + (size_t)t*D);
  float acc[E];
#pragma unroll
  for (int e=0;e<E;e++) acc[e]=0.f;
#pragma unroll
  for (int i=0;i<4;i++){
    float4 xv = xp[lane + (i<<6)];
    ushort4 o; o.x=f2h_bits(xv.x); o.y=f2h_bits(xv.y); o.z=f2h_bits(xv.z); o.w=f2h_bits(xv.w);
    xo[lane + (i<<6)] = o;
#pragma unroll
    for (int e=0;e<E;e++){
      float4 wv = ((const float4*)(rw + e*D))[lane + (i<<6)];
      acc[e] = fmaf(xv.x,wv.x, fmaf(xv.y,wv.y, fmaf(xv.z,wv.z, fmaf(xv.w,wv.w, acc[e]))));
    }
  }
#pragma unroll
  for (int e=0;e<E;e++){
#pragma unroll
    for (int off=32; off>0; off>>=1) acc[e] += __shfl_xor(acc[e], off);
  }
  if (lane==0){
    float l0=-1e30f, l1=-1e30f; int e0=0, e1=0;
#pragma unroll
    for (int e=0;e<E;e++){
      float v = acc[e];
      if (v > l0){ l1=l0; e1=e0; l0=v; e0=e; }
      else if (v > l1){ l1=v; e1=e; }
    }
    float r   = expf(l1 - l0);          // p1/p0
    float inv = 1.f/(1.f + r);
    tok_e[2*t]   = e0; tok_e[2*t+1] = e1;
    tok_w[2*t]   = inv; tok_w[2*t+1] = r*inv;
    atomicAdd(&counts[e0], 1);
    atomicAdd(&counts[e1], 1);
  }
}

// ---------------- scan: offsets + row-tile map (9 groups, 256-row tiles) ----------------
__global__ void scan_kernel(const int* __restrict__ counts, int* __restrict__ offs,
                            int* __restrict__ tile_g, int* __restrict__ tile_r0,
                            int* __restrict__ nrt){
  if (blockIdx.x==0 && threadIdx.x==0){
    int off=0, nt=0;
    for (int e=0;e<E;e++){
      offs[e]=off;
      int c = counts[e];
      int tiles = (c+255)>>8;
      for (int i=0;i<tiles;i++){ tile_g[nt]=e; tile_r0[nt]=off + (i<<8); nt++; }
      off += c;
    }
    offs[E] = off;                       // == 2T
    for (int i=0;i<T/256;i++){ tile_g[nt]=E; tile_r0[nt]=2*T + (i<<8); nt++; }
    offs[E+1] = 3*T;
    *nrt = nt;
  }
}

// ---------------- scatter: grouped row -> token; inverse map token -> grouped rows ----------------
__global__ __launch_bounds__(256) void scatter_kernel(const int* __restrict__ tok_e,
    const float* __restrict__ tok_w, const int* __restrict__ offs,
    int* __restrict__ fill, int* __restrict__ row_tok, float* __restrict__ row_w,
    int* __restrict__ inv2){
  int idx = blockIdx.x*256 + threadIdx.x;   // [0, 3T)
  if (idx < 2*T){
    int e = tok_e[idx];
    int pos = offs[e] + atomicAdd(&fill[e], 1);
    row_tok[pos] = idx >> 1;
    row_w[pos]   = tok_w[idx];
    inv2[idx]    = pos;                     // inv2[2*token + slot]
  } else {
    row_tok[idx] = idx - 2*T;
    row_w[idx]   = 1.0f;
  }
}

// ---- grouped GEMM, 256x256 tile, BK=64, ring-2 LDS (128 KB), DEEP counted vmcnt:
//      4 phases/K-tile; phase = {VMW? -> bar -> ds_read frags || stage 1 half-tile -> 16 MFMA}.
//      Stage of (t+1,h) is issued 4 phases before its VMW -> HBM latency fully hidden.
//      In-flight 4-8 loads steady; single vmcnt(0) drain at last tile only.
//      Hazards: (a) stage(t,h) -> read(t,h): own VMW retires own loads, barrier conjoins all
//      waves; (b) read(t-1) -> overwrite by stage(t+1): each wave's reads complete (lgkm)
//      before its last t-1 MFMA issues, which precedes tile-t p1 barrier; stages execute
//      after that barrier.
// MODE 0: FC  (A = xb gathered via row_tok, out = relu(acc)^2 -> h f16)
// MODE 1: PROJ(A = h grouped-contiguous,    out = raw acc -> y f16; weights in combine)
template<int MODE>
__global__ __launch_bounds__(512, 2) void gemm8p_kernel(
    const unsigned short* __restrict__ A, const unsigned short* __restrict__ Ball,
    unsigned short* __restrict__ O,
    const int K, const int N, const int CT,
    const int* __restrict__ tile_g, const int* __restrict__ tile_r0,
    const int* __restrict__ offs, const int* __restrict__ nrt,
    const int* __restrict__ row_tok)
{
  // T1: bijective XCD swizzle on linearized wg id (m204 form)
  const int nwg  = gridDim.x * gridDim.y;
  const int orig = blockIdx.y * gridDim.x + blockIdx.x;
  const int q8 = nwg >> 3, r8 = nwg & 7;
  const int xcd = orig & 7, pos = orig >> 3;
  const int wg = (xcd < r8 ? xcd*(q8+1) : r8*(q8+1) + (xcd-r8)*q8) + pos;
  const int rt = wg / CT, ct = wg - rt*CT;
  if (rt >= *nrt) return;

  const int g    = tile_g[rt];
  const int row0 = tile_r0[rt];
  const int row_end = offs[g+1];
  const unsigned short* Bp = Ball + (size_t)g * (size_t)N * (size_t)K;

  // HT(buf,ks) base = (buf*2+ks)*8192 shorts; each HT = [256 rows][4 x 16B chunks] (k-half)
  __shared__ __align__(16) unsigned short As[2*2*8192];
  __shared__ __align__(16) unsigned short Bs[2*2*8192];

  const int tid  = threadIdx.x;
  const int lane = tid & 63;
  const int wave = tid >> 6;

  // --- staging map: slot s = c*512+tid; row rr = s>>2; local chunk = s&3;
  //     inverse-swizzled global chunk qg = (s&3) ^ ((rr>>1)&3)   (0-conflict family, r1-r5)
  const unsigned short* aS[2];
  const unsigned short* bS[2];
  int ldst[2];
#pragma unroll
  for (int c=0;c<2;c++){
    int s  = (c<<9) + tid;
    int rr = s >> 2;
    int qg = (s & 3) ^ ((rr >> 1) & 3);
    int ar = (MODE==0) ? row_tok[row0 + rr] : (row0 + rr);  // row_tok valid on [0,3T)
    aS[c] = A  + (size_t)ar*K + qg*8;
    bS[c] = Bp + (size_t)((ct<<8) + rr)*K + qg*8;
    ldst[c] = ((c<<9) + (wave<<6))*8;        // wave-uniform LDS base (lane*16B implicit)
  }

#define STAGE_A(KT,KS) { _Pragma("unroll") for (int c=0;c<2;c++) \
    gload_lds16(aS[c] + (KT)*64 + (KS)*32, As + ((((KT)&1)*2+(KS))<<13) + ldst[c]); }
#define STAGE_B(KT,KS) { _Pragma("unroll") for (int c=0;c<2;c++) \
    gload_lds16(bS[c] + (KT)*64 + (KS)*32, Bs + ((((KT)&1)*2+(KS))<<13) + ldst[c]); }

  // --- fragment read offsets within a half-tile [256][32] shorts (swizzle matches staging)
  const int wm = wave >> 2, wn = wave & 3;   // 2x4 waves, per-wave output 128 x 64
  const int q16g = lane >> 4;
  int aoff[8], boff[4];
#pragma unroll
  for (int m=0;m<8;m++){
    int r = (wm<<7) + (m<<4) + (lane&15);
    aoff[m] = (r<<5) + ((q16g ^ ((r>>1)&3))<<3);
  }
#pragma unroll
  for (int n=0;n<4;n++){
    int r = (wn<<6) + (n<<4) + (lane&15);
    boff[n] = (r<<5) + ((q16g ^ ((r>>1)&3))<<3);
  }

#define BARS { __builtin_amdgcn_s_barrier(); __builtin_amdgcn_sched_barrier(0); }
#define VMW(NN) asm volatile("s_waitcnt vmcnt(" #NN ")" ::: "memory");
#define DSA_LO(BUF,KS) { const unsigned short* hb = As + (((BUF)*2+(KS))<<13); \
    _Pragma("unroll") for (int m=0;m<4;m++) af[m] = *(const f16x8*)(hb + aoff[m]); }
#define DSA_HI(BUF,KS) { const unsigned short* hb = As + (((BUF)*2+(KS))<<13); \
    _Pragma("unroll") for (int m=0;m<4;m++) ag[m] = *(const f16x8*)(hb + aoff[4+m]); }
#define DSB_(BUF,KS) { const unsigned short* hb = Bs + (((BUF)*2+(KS))<<13); \
    _Pragma("unroll") for (int n=0;n<4;n++) bf[n] = *(const f16x8*)(hb + boff[n]); }
#define MFMA16(AR,SRC) { __builtin_amdgcn_s_setprio(1); \
    _Pragma("unroll") for (int m=0;m<4;m++) \
    _Pragma("unroll") for (int n=0;n<4;n++) \
      acc[(AR)*4+m][n] = __builtin_amdgcn_mfma_f32_16x16x32_f16(SRC[m], bf[n], acc[(AR)*4+m][n], 0, 0, 0); \
    __builtin_amdgcn_s_setprio(0); }

  f32x4 acc[8][4] = {};
  const int nkt = K >> 6;                    // 64-wide K tiles (16 FC / 64 PROJ)

  // prologue: stage K-tile 0 fully (8 loads in flight; issue order A0,B0,A1,B1)
  STAGE_A(0,0); STAGE_B(0,0); STAGE_A(0,1); STAGE_B(0,1);

  f16x8 af[4], ag[4], bf[4];
  for (int t=0; t<nkt; ++t){
    const int b = t & 1;
    const bool more = (t+1 < nkt);
    // ---- p1: retire (t,0) [issued 4 phases ago]; read lo-half frags kk0; stage A(t+1,0)
    VMW(4); BARS;
    DSA_LO(b,0); DSB_(b,0);
    if (more) STAGE_A(t+1,0);
    MFMA16(0, af);
    // ---- p2: read hi-half A kk0 (B reused in regs); stage B(t+1,0)
    BARS;
    DSA_HI(b,0);
    if (more) STAGE_B(t+1,0);
    MFMA16(1, ag);
    // ---- p3: retire (t,1); read lo kk1; stage A(t+1,1)
    if (more) { VMW(4); } else { VMW(0); }
    BARS;
    DSA_LO(b,1); DSB_(b,1);
    if (more) STAGE_A(t+1,1);
    MFMA16(0, af);
    // ---- p4: read hi kk1; stage B(t+1,1)
    BARS;
    DSA_HI(b,1);
    if (more) STAGE_B(t+1,1);
    MFMA16(1, ag);
  }

  // --- epilogue: C row = (lane>>4)*4 + q, col = lane&15 within each 16x16 fragment
  const int lcol = lane & 15;
  const int lrow = (lane >> 4) << 2;
#pragma unroll
  for (int m=0;m<8;m++){
#pragma unroll
    for (int q=0;q<4;q++){
      const int grow = row0 + (wm<<7) + (m<<4) + lrow + q;
      if (grow >= row_end) continue;           // padded tile rows
#pragma unroll
      for (int n=0;n<4;n++){
        const int col = (ct<<8) + (wn<<6) + (n<<4) + lcol;
        float v = acc[m][n][q];
        if constexpr (MODE==0) v = (v > 0.f) ? v*v : 0.f;   // relu(x)^2
        O[(size_t)grow*N + col] = f2h_bits(v);
      }
    }
  }
#undef STAGE_A
#undef STAGE_B
#undef BARS
#undef VMW
#undef DSA_LO
#undef DSA_HI
#undef DSB_
#undef MFMA16
}

// ---------------- combine: out[t] = w0*y[p0] + w1*y[p1] + y[shared_t] ----------------
__global__ __launch_bounds__(256) void combine_kernel(const unsigned short* __restrict__ y,
    const int* __restrict__ inv2, const float* __restrict__ row_w, float* __restrict__ out){
  int gid = blockIdx.x*256 + threadIdx.x;    // T*128 threads, 8 cols each
  int t = gid >> 7, c = gid & 127;
  int p0 = inv2[2*t], p1 = inv2[2*t+1];
  float w0 = row_w[p0], w1 = row_w[p1];
  f16x8 v0 = *(const f16x8*)(y + (size_t)p0*D      + c*8);
  f16x8 v1 = *(const f16x8*)(y + (size_t)p1*D      + c*8);
  f16x8 v2 = *(const f16x8*)(y + (size_t)(2*T+t)*D + c*8);
  float4 o0, o1;
  float r[8];
#pragma unroll
  for (int j=0;j<8;j++)
    r[j] = fmaf(w0, (float)v0[j], fmaf(w1, (float)v1[j], (float)v2[j]));
  o0.x=r[0]; o0.y=r[1]; o0.z=r[2]; o0.w=r[3];
  o1.x=r[4]; o1.y=r[5]; o1.z=r[6]; o1.w=r[7];
  float4* op = (float4*)(out + (size_t)t*D + c*8);
  op[0] = o0; op[1] = o1;
}

// ---------------- host launcher ----------------
extern "C" void kernel_launch(void* const* d_in, const int* in_sizes, int n_in,
                              void* d_out, int out_size, void* d_ws, size_t ws_size,
                              hipStream_t stream){
  const float* x     = (const float*)d_in[0];
  const float* rw    = (const float*)d_in[1];
  const float* wfc   = (const float*)d_in[2];
  const float* wproj = (const float*)d_in[3];
  const float* sfc   = (const float*)d_in[4];
  const float* sproj = (const float*)d_in[5];
  float* out = (float*)d_out;

  char* ws = (char*)d_ws;
  size_t off = 0;
  auto alloc = [&](size_t bytes)->void*{
    void* p = ws + off; off += (bytes + 255) & ~(size_t)255; return p;
  };
  unsigned short* xb    = (unsigned short*)alloc((size_t)T*D*2);
  unsigned short* wall  = (unsigned short*)alloc((size_t)NG*DFF*D*2);  // experts 0..7 then shared
  unsigned short* wpall = (unsigned short*)alloc((size_t)NG*D*DFF*2);
  unsigned short* h     = (unsigned short*)alloc((size_t)RTOT*DFF*2);
  int*   tok_e   = (int*)  alloc((size_t)T*2*4);
  float* tok_w   = (float*)alloc((size_t)T*2*4);
  int*   row_tok = (int*)  alloc((size_t)RTOT*4);
  float* row_w   = (float*)alloc((size_t)RTOT*4);
  int*   inv2    = (int*)  alloc((size_t)2*T*4);
  int* counts  = (int*)alloc(E*4);
  int* fill    = (int*)alloc(E*4);
  int* offs    = (int*)alloc((E+2)*4);
  int* nrt     = (int*)alloc(4);
  int* tile_g  = (int*)alloc(MAXRT*4);
  int* tile_r0 = (int*)alloc(MAXRT*4);
  if (off > ws_size) return;   // visible failure if workspace too small

  // y [3T][D] f16 aliases wall: FC (last reader of wall) completes before PROJ writes y.
  unsigned short* y = wall;    // 50 MB needed, 75 MB available

  hipMemsetAsync(counts, 0, E*4, stream);
  hipMemsetAsync(fill,   0, E*4, stream);

  // single fused weight-cast dispatch (x cast fused into router)
  cast_all_kernel<<<2048, 256, 0, stream>>>(
      wfc, sfc, wproj, sproj,
      wall, wall + (size_t)E*DFF*D, wpall, wpall + (size_t)E*D*DFF,
      E*DFF*D/4, DFF*D/4, E*D*DFF/4, D*DFF/4);

  // routing
  router_kernel <<<T/4, 256, 0, stream>>>(x, rw, xb, tok_e, tok_w, counts);
  scan_kernel   <<<1,   64,  0, stream>>>(counts, offs, tile_g, tile_r0, nrt);
  scatter_kernel<<<RTOT/256, 256, 0, stream>>>(tok_e, tok_w, offs, fill, row_tok, row_w, inv2);

  // FC: h = relu(x @ w_fc^T)^2 for all grouped rows (incl. shared)
  gemm8p_kernel<0><<<dim3(DFF/256, MAXRT), 512, 0, stream>>>(
      xb, wall, h, D, DFF, DFF/256, tile_g, tile_r0, offs, nrt, row_tok);
  // PROJ: y = h @ w_proj^T (raw, unweighted)
  gemm8p_kernel<1><<<dim3(D/256, MAXRT), 512, 0, stream>>>(
      h, wpall, y, DFF, D, D/256, tile_g, tile_r0, offs, nrt, row_tok);
  // combine: weighted sum per token
  combine_kernel<<<(T*128)/256, 256, 0, stream>>>(y, inv2, row_w, out);
}